// Round 14
// baseline (772.332 us; speedup 1.0000x reference)
//
#include <hip/hip_runtime.h>
#include <hip/hip_bf16.h>

// NodeGCN: GCNConv + 2x GINConv (edge-attr MLPs) + BN + concat + 2-layer head.
// Round 14: ILP experiment — each wave processes TWO nodes (2p, 2p+1) with
// interleaved chains: both batches' gathers issued together, GEMM1 A/B into
// separate s_t slices, one barrier, both exchanges, both GEMM2+epilogues.
// B's memory latency hides under A's compute. Rounds/pair = max(nA,nB) ~1.75
// vs 2.8 sequential. Node pipeline = R10 best config (596us total).

#define HH 96
#define EDGEF 16
#define CAT (3 * HH)

typedef __attribute__((ext_vector_type(8))) short bf16x8;
typedef __attribute__((ext_vector_type(4))) float f32x4;
typedef __attribute__((ext_vector_type(4))) unsigned short ubf16x4;
typedef __attribute__((ext_vector_type(2))) unsigned uint2v;

typedef union { bf16x8 v; unsigned u[4]; } bfpack8;
typedef union { ubf16x4 v; unsigned u[2]; } bfpack4;

__device__ __forceinline__ unsigned short f2bf(float f) {
    unsigned u = __float_as_uint(f);
    u += 0x7fffu + ((u >> 16) & 1u);      // round-to-nearest-even
    return (unsigned short)(u >> 16);
}
__device__ __forceinline__ float bf2f(unsigned short s) {
    return __uint_as_float(((unsigned)s) << 16);
}
// packed f32x2 -> bf16x2 (RNE, v_cvt_pk_bf16_f32); lo 16 bits = lo input
__device__ __forceinline__ unsigned pkbf2(float lo, float hi) {
    __hip_bfloat162 b = __float22bfloat162_rn(make_float2(lo, hi));
    union { __hip_bfloat162 b2; unsigned u; } cv; cv.b2 = b; return cv.u;
}

// ---------------- unified MFMA node GEMM (layer0 / head) --------------------------
// AMODE: 0 = f32 A; 1 = bf16 A.  EPI: 0 = f32 C; 1 = relu->bf16 C; 3 = f32 C + bf16 copy
template <int K, int F, int AMODE, int EPI>
__global__ __launch_bounds__(256) void node_gemm(
    const void* __restrict__ Aptr, int lda,
    const float* __restrict__ W, const float* __restrict__ bias,
    void* __restrict__ Cptr, int ldc,
    unsigned short* __restrict__ bf_copy,
    int M)
{
    constexpr int SW = ((K * 2) % 128 == 0) ? 7 : 3;
    constexpr int NFT = F / 16;
    __shared__ __align__(16) short s_wt[F * K];

    const int tid = threadIdx.x;
    const int lane = tid & 63;
    const int w = tid >> 6;
    const int lr = lane & 15;
    const int lg = lane >> 4;

    for (int idx = tid; idx < F * K; idx += 256) {
        int f = idx / K, k = idx - f * K;
        s_wt[idx ^ ((f & SW) << 3)] = (short)f2bf(W[k * F + f]);
    }
    __syncthreads();

    const int R0 = blockIdx.x * 64 + 16 * w;
    const int Ra = min(R0 + lr, M - 1);

    f32x4 acc[NFT];
#pragma unroll
    for (int ft = 0; ft < NFT; ++ft) {
        float b = bias[16 * ft + lr];
        acc[ft][0] = b; acc[ft][1] = b; acc[ft][2] = b; acc[ft][3] = b;
    }

#pragma unroll
    for (int kt = 0; kt < K / 32; ++kt) {
        bf16x8 ae;
        if (AMODE == 0) {
            const float* ap = (const float*)Aptr + (size_t)Ra * lda + 32 * kt + 8 * lg;
            f32x4 a0 = *(const f32x4*)ap;
            f32x4 a1 = *(const f32x4*)(ap + 4);
            bfpack8 p;
            p.u[0] = pkbf2(a0[0], a0[1]); p.u[1] = pkbf2(a0[2], a0[3]);
            p.u[2] = pkbf2(a1[0], a1[1]); p.u[3] = pkbf2(a1[2], a1[3]);
            ae = p.v;
        } else {
            ae = *(const bf16x8*)((const unsigned short*)Aptr + (size_t)Ra * lda + 32 * kt + 8 * lg);
        }
#pragma unroll
        for (int ft = 0; ft < NFT; ++ft) {
            bf16x8 bw = *(const bf16x8*)&s_wt[((lr + 16 * ft) * K + 32 * kt + 8 * lg) ^ ((lr & SW) << 3)];
            acc[ft] = __builtin_amdgcn_mfma_f32_16x16x32_bf16(ae, bw, acc[ft], 0, 0, 0);
        }
    }

#pragma unroll
    for (int reg = 0; reg < 4; ++reg) {
        int r = R0 + 4 * lg + reg;
        if (r < M) {
#pragma unroll
            for (int ft = 0; ft < NFT; ++ft) {
                int col = 16 * ft + lr;
                float v = acc[ft][reg];
                if (EPI == 0) {
                    ((float*)Cptr)[(size_t)r * ldc + col] = v;
                } else if (EPI == 1) {
                    ((unsigned short*)Cptr)[(size_t)r * ldc + col] = f2bf(fmaxf(v, 0.f));
                } else {
                    ((float*)Cptr)[(size_t)r * ldc + col] = v;
                    bf_copy[(size_t)r * F + col] = f2bf(v);
                }
            }
        }
    }
}

// ---------------- fused GIN MLP: z=(1+eps)h+agg; out=BN(relu(relu(z@W1+b1)@W2+b2)) --
__global__ __launch_bounds__(256) void gin_mlp(
    const unsigned short* __restrict__ hb_in,   // dense [N][96] bf16
    const float* __restrict__ agg,              // dense [N][96] f32
    const float* __restrict__ eps_arr, int li,
    const float* __restrict__ mw1, const float* __restrict__ mb1,
    const float* __restrict__ mw2, const float* __restrict__ mb2,
    const float* __restrict__ gamma, const float* __restrict__ beta,
    const float* __restrict__ mean, const float* __restrict__ var,
    unsigned short* __restrict__ featsbf, int slot,
    unsigned short* __restrict__ hb_out,
    int M)
{
    __shared__ __align__(16) short s_w1t[96][104];   // mw1^T bf16 [f][k]
    __shared__ __align__(16) short s_w2t[96][104];   // mw2^T bf16 [f][k]
    __shared__ __align__(16) short s_z[4][16][104];  // per-wave z1 tile
    __shared__ float s_b[192];                       // mb1 | mb2

    const int tid = threadIdx.x;
    const int lane = tid & 63;
    const int w = tid >> 6;
    const int lr = lane & 15;
    const int lg = lane >> 4;

    for (int idx = tid; idx < HH * HH; idx += 256) {
        int k = idx / HH, f = idx - k * HH;
        s_w1t[f][k] = (short)f2bf(mw1[idx]);
        s_w2t[f][k] = (short)f2bf(mw2[idx]);
    }
    if (tid < HH) { s_b[tid] = mb1[tid]; s_b[HH + tid] = mb2[tid]; }
    __syncthreads();

    const int R0 = blockIdx.x * 64 + 16 * w;
    const int Ra = min(R0 + lr, M - 1);
    const float e1 = 1.f + eps_arr[li];

    // input B-frags (z^T)
    bf16x8 inf[3];
#pragma unroll
    for (int kt = 0; kt < 3; ++kt) {
        const unsigned short* hp = hb_in + (size_t)Ra * HH + 32 * kt + 8 * lg;
        bf16x8 h8 = *(const bf16x8*)hp;
        const float* gp = agg + (size_t)Ra * HH + 32 * kt + 8 * lg;
        f32x4 g0 = *(const f32x4*)gp;
        f32x4 g1 = *(const f32x4*)(gp + 4);
        float t0 = fmaf(e1, bf2f((unsigned short)h8[0]), g0[0]);
        float t1 = fmaf(e1, bf2f((unsigned short)h8[1]), g0[1]);
        float t2 = fmaf(e1, bf2f((unsigned short)h8[2]), g0[2]);
        float t3 = fmaf(e1, bf2f((unsigned short)h8[3]), g0[3]);
        float t4 = fmaf(e1, bf2f((unsigned short)h8[4]), g1[0]);
        float t5 = fmaf(e1, bf2f((unsigned short)h8[5]), g1[1]);
        float t6 = fmaf(e1, bf2f((unsigned short)h8[6]), g1[2]);
        float t7 = fmaf(e1, bf2f((unsigned short)h8[7]), g1[3]);
        bfpack8 p;
        p.u[0] = pkbf2(t0, t1); p.u[1] = pkbf2(t2, t3);
        p.u[2] = pkbf2(t4, t5); p.u[3] = pkbf2(t6, t7);
        inf[kt] = p.v;
    }

    // GEMM1 swapped: D = z1^T, mb1 C-init
#pragma unroll
    for (int ft = 0; ft < 6; ++ft) {
        f32x4 t4v = *(const f32x4*)&s_b[16 * ft + 4 * lg];
#pragma unroll
        for (int kt = 0; kt < 3; ++kt) {
            bf16x8 aw = *(const bf16x8*)&s_w1t[16 * ft + lr][32 * kt + 8 * lg];
            t4v = __builtin_amdgcn_mfma_f32_16x16x32_bf16(aw, inf[kt], t4v, 0, 0, 0);
        }
        uint2v uu;
        uu[0] = pkbf2(fmaxf(t4v[0], 0.f), fmaxf(t4v[1], 0.f));
        uu[1] = pkbf2(fmaxf(t4v[2], 0.f), fmaxf(t4v[3], 0.f));
        *(uint2v*)&s_z[w][lr][16 * ft + 4 * lg] = uu;
    }
    __builtin_amdgcn_wave_barrier();

    // GEMM2 normal
    bf16x8 az[3];
#pragma unroll
    for (int kt = 0; kt < 3; ++kt)
        az[kt] = *(const bf16x8*)&s_z[w][lr][32 * kt + 8 * lg];

    f32x4 acc[6];
#pragma unroll
    for (int ft = 0; ft < 6; ++ft) {
        float b = s_b[HH + 16 * ft + lr];
        acc[ft][0] = b; acc[ft][1] = b; acc[ft][2] = b; acc[ft][3] = b;
#pragma unroll
        for (int kt = 0; kt < 3; ++kt) {
            bf16x8 bw = *(const bf16x8*)&s_w2t[16 * ft + lr][32 * kt + 8 * lg];
            acc[ft] = __builtin_amdgcn_mfma_f32_16x16x32_bf16(az[kt], bw, acc[ft], 0, 0, 0);
        }
    }

    float scale[6], shiftv[6];
#pragma unroll
    for (int ft = 0; ft < 6; ++ft) {
        int col = 16 * ft + lr;
        float s = gamma[col] * rsqrtf(var[col] + 1e-5f);
        scale[ft] = s;
        shiftv[ft] = beta[col] - mean[col] * s;
    }
#pragma unroll
    for (int reg = 0; reg < 4; ++reg) {
        int r = R0 + 4 * lg + reg;
        if (r < M) {
#pragma unroll
            for (int ft = 0; ft < 6; ++ft) {
                int col = 16 * ft + lr;
                float z = fmaxf(acc[ft][reg], 0.f) * scale[ft] + shiftv[ft];
                unsigned short zb = f2bf(z);
                featsbf[(size_t)r * CAT + slot * HH + col] = zb;
                hb_out[(size_t)r * HH + col] = zb;
            }
        }
    }
}

// ---------------- CSR build (fused) ----------------------------------------------
__global__ void init_kernel(float* __restrict__ deg, int* __restrict__ cnt, int N)
{
    int i = blockIdx.x * blockDim.x + threadIdx.x;
    if (i < N) { deg[i] = 1.f; cnt[i] = 0; }
}

__global__ void count_kernel(const int* __restrict__ row, const int* __restrict__ col,
                             float* __restrict__ deg, int* __restrict__ cnt, int E)
{
    int e = blockIdx.x * blockDim.x + threadIdx.x;
    if (e < E) {
        atomicAdd(&deg[row[e]], 1.f);
        atomicAdd(&cnt[col[e]], 1);
    }
}

__global__ void scan1_kernel(const int* __restrict__ cnt, int* __restrict__ start,
                             int* __restrict__ bsum, int N)
{
    __shared__ int s[256];
    int tid = threadIdx.x;
    int i = blockIdx.x * 256 + tid;
    int v = (i < N) ? cnt[i] : 0;
    s[tid] = v;
    __syncthreads();
#pragma unroll
    for (int off = 1; off < 256; off <<= 1) {
        int t = (tid >= off) ? s[tid - off] : 0;
        __syncthreads();
        s[tid] += t;
        __syncthreads();
    }
    if (i < N) start[i] = s[tid] - v;
    if (tid == 255) bsum[blockIdx.x] = s[255];
}

__global__ void scan2_kernel(int* __restrict__ bsum, int nb)
{
    __shared__ int s[256];
    int tid = threadIdx.x;
    int v = (tid < nb) ? bsum[tid] : 0;
    s[tid] = v;
    __syncthreads();
#pragma unroll
    for (int off = 1; off < 256; off <<= 1) {
        int t = (tid >= off) ? s[tid - off] : 0;
        __syncthreads();
        s[tid] += t;
        __syncthreads();
    }
    if (tid < nb) bsum[tid] = s[tid] - v;
}

__global__ void scan3_kernel(int* __restrict__ start, const int* __restrict__ bsum,
                             int* __restrict__ cursor,
                             const float* __restrict__ deg, float* __restrict__ dinv,
                             int N, int E)
{
    int i = blockIdx.x * blockDim.x + threadIdx.x;
    if (i < N) {
        int f = start[i] + bsum[i >> 8];
        start[i] = f;
        cursor[i] = f;
        dinv[i] = rsqrtf(deg[i]);
    } else if (i == N) {
        start[N] = E;
    }
}

// scatter + edge_attr permute+cvt fused
__global__ void scatter_ea_kernel(const int* __restrict__ row, const int* __restrict__ col,
                                  int* __restrict__ cursor,
                                  const float* __restrict__ ea,
                                  int* __restrict__ row_sorted,
                                  unsigned short* __restrict__ eas, int E)
{
    int e = blockIdx.x * blockDim.x + threadIdx.x;
    if (e >= E) return;
    int c = col[e];
    int p = atomicAdd(&cursor[c], 1);
    row_sorted[p] = row[e];
    const float* src = ea + (size_t)e * EDGEF;
    f32x4 v0 = *(const f32x4*)(src);
    f32x4 v1 = *(const f32x4*)(src + 4);
    f32x4 v2 = *(const f32x4*)(src + 8);
    f32x4 v3 = *(const f32x4*)(src + 12);
    bfpack8 o0, o1;
    o0.u[0] = pkbf2(v0[0], v0[1]); o0.u[1] = pkbf2(v0[2], v0[3]);
    o0.u[2] = pkbf2(v1[0], v1[1]); o0.u[3] = pkbf2(v1[2], v1[3]);
    o1.u[0] = pkbf2(v2[0], v2[1]); o1.u[1] = pkbf2(v2[2], v2[3]);
    o1.u[2] = pkbf2(v3[0], v3[1]); o1.u[3] = pkbf2(v3[2], v3[3]);
    *(bf16x8*)(eas + (size_t)p * EDGEF) = o0.v;
    *(bf16x8*)(eas + (size_t)p * EDGEF + 8) = o1.v;
}

// ---------------- node-centric MFMA edge kernel (2 nodes per wave, ILP) ----------
// R10 body per chain; wave owns nodes (2p, 2p+1) with interleaved rounds:
// both gathers issued together, GEMM1 A/B -> s_t slices 0/1, one barrier, both
// exchanges, both GEMM2+epilogues. LDS 47360B (3 blocks/CU); VGPR ~140 under
// the (256,3)=168 cap (WRITE_SIZE = spill tripwire).
template <bool GCN>
__global__ __launch_bounds__(256, 3) void edge_kernel(
    const unsigned short* __restrict__ ea_sorted,
    const int* __restrict__ row_sorted,
    const int* __restrict__ seg_start,
    const float* __restrict__ bw1, const float* __restrict__ bb1,
    const float* __restrict__ bw2, const float* __restrict__ bb2,
    const unsigned short* __restrict__ hbf,
    const float* __restrict__ dinv,
    float* __restrict__ agg,
    int N)
{
    __shared__ __align__(16) short s_bw2T[96][104];     // 19968B
    __shared__ __align__(16) short s_t[4][2][16][104];  // 26624B: per-wave A/B slices
    __shared__ float s_bias[192];                       //   768B

    const int tid = threadIdx.x;
    const int lane = tid & 63;
    const int w = tid >> 6;
    const int lr = lane & 15;
    const int lg = lane >> 4;

    for (int idx = tid; idx < HH * HH; idx += 256) {
        int k = idx / HH, f = idx - k * HH;
        s_bw2T[f][k] = (short)f2bf(bw2[idx]);
    }
    if (tid < HH) { s_bias[tid] = bb1[tid]; s_bias[HH + tid] = bb2[tid]; }

    // persistent bw1^T A-frags straight from global (zero for k>=16, lg>=2)
    bf16x8 bwf[6];
#pragma unroll
    for (int ft = 0; ft < 6; ++ft) {
        bf16x8 z;
#pragma unroll
        for (int j = 0; j < 8; ++j) z[j] = 0;
        if (lg < 2) {
#pragma unroll
            for (int j = 0; j < 8; ++j)
                z[j] = (short)f2bf(bw1[(8 * lg + j) * HH + lr + 16 * ft]);
        }
        bwf[ft] = z;
    }
    __syncthreads();

    const int nwaves = gridDim.x * 4;

    for (int p = blockIdx.x * 4 + w; 2 * p < N; p += nwaves) {
        const int cA = 2 * p;
        const int cB = min(2 * p + 1, N - 1);
        const int s0A = seg_start[cA], s1A = seg_start[cA + 1];
        const int s0B = seg_start[cB], s1B = seg_start[cB + 1];
        const float dcA = GCN ? dinv[cA] : 1.f;
        const float dcB = GCN ? dinv[cB] : 1.f;

        f32x4 accA[6], accB[6];
#pragma unroll
        for (int ft = 0; ft < 6; ++ft) {
            accA[ft][0]=0.f; accA[ft][1]=0.f; accA[ft][2]=0.f; accA[ft][3]=0.f;
            accB[ft][0]=0.f; accB[ft][1]=0.f; accB[ft][2]=0.f; accB[ft][3]=0.f;
        }

        int bA = s0A, bB = s0B;
        while (bA < s1A || bB < s1B) {
            const bool doA = bA < s1A;
            const bool doB = bB < s1B;

            // ---- issue both chains' loads up front ----
            ubf16x4 hvA[6], hvB[6];
            bf16x8 aeA, aeB;
            float mskA = 0.f, mskB = 0.f;
            if (doA) {
                const int ep = bA + lr;
                const bool v = ep < s1A;
                const int ec = v ? ep : s0A;
                const int r = row_sorted[ec];
                const unsigned short* hrow = hbf + (size_t)r * HH + 4 * lg;
#pragma unroll
                for (int ft = 0; ft < 6; ++ft) hvA[ft] = *(const ubf16x4*)(hrow + 16 * ft);
                mskA = v ? (GCN ? dinv[r] * dcA : 1.f) : 0.f;
                aeA = *(const bf16x8*)(ea_sorted + (size_t)ec * EDGEF + 8 * (lg & 1));
            }
            if (doB) {
                const int ep = bB + lr;
                const bool v = ep < s1B;
                const int ec = v ? ep : s0B;
                const int r = row_sorted[ec];
                const unsigned short* hrow = hbf + (size_t)r * HH + 4 * lg;
#pragma unroll
                for (int ft = 0; ft < 6; ++ft) hvB[ft] = *(const ubf16x4*)(hrow + 16 * ft);
                mskB = v ? (GCN ? dinv[r] * dcB : 1.f) : 0.f;
                aeB = *(const bf16x8*)(ea_sorted + (size_t)ec * EDGEF + 8 * (lg & 1));
            }

            // ---- GEMM1 for both chains into separate slices ----
            if (doA) {
#pragma unroll
                for (int ft = 0; ft < 6; ++ft) {
                    f32x4 ci = *(const f32x4*)&s_bias[16 * ft + 4 * lg];
                    f32x4 t4 = __builtin_amdgcn_mfma_f32_16x16x32_bf16(bwf[ft], aeA, ci, 0, 0, 0);
                    uint2v uu;
                    uu[0] = pkbf2(fmaxf(t4[0], 0.f), fmaxf(t4[1], 0.f));
                    uu[1] = pkbf2(fmaxf(t4[2], 0.f), fmaxf(t4[3], 0.f));
                    *(uint2v*)&s_t[w][0][lr][16 * ft + 4 * lg] = uu;
                }
            }
            if (doB) {
#pragma unroll
                for (int ft = 0; ft < 6; ++ft) {
                    f32x4 ci = *(const f32x4*)&s_bias[16 * ft + 4 * lg];
                    f32x4 t4 = __builtin_amdgcn_mfma_f32_16x16x32_bf16(bwf[ft], aeB, ci, 0, 0, 0);
                    uint2v uu;
                    uu[0] = pkbf2(fmaxf(t4[0], 0.f), fmaxf(t4[1], 0.f));
                    uu[1] = pkbf2(fmaxf(t4[2], 0.f), fmaxf(t4[3], 0.f));
                    *(uint2v*)&s_t[w][1][lr][16 * ft + 4 * lg] = uu;
                }
            }
            __builtin_amdgcn_wave_barrier();    // t writes before bt reads

            bf16x8 btA[3], btB[3];
            if (doA) {
#pragma unroll
                for (int kt = 0; kt < 3; ++kt)
                    btA[kt] = *(const bf16x8*)&s_t[w][0][lr][8 * lg + 32 * kt];
            }
            if (doB) {
#pragma unroll
                for (int kt = 0; kt < 3; ++kt)
                    btB[kt] = *(const bf16x8*)&s_t[w][1][lr][8 * lg + 32 * kt];
            }

            // ---- GEMM2 + epilogue, chain A then chain B ----
            if (doA) {
#pragma unroll
                for (int ft = 0; ft < 6; ++ft) {
                    const int fb = 16 * ft + 4 * lg;
                    f32x4 ee = *(const f32x4*)&s_bias[HH + fb];
#pragma unroll
                    for (int kt = 0; kt < 3; ++kt) {
                        bf16x8 aw = *(const bf16x8*)&s_bw2T[lr + 16 * ft][8 * lg + 32 * kt];
                        ee = __builtin_amdgcn_mfma_f32_16x16x32_bf16(aw, btA[kt], ee, 0, 0, 0);
                    }
#pragma unroll
                    for (int reg = 0; reg < 4; ++reg) {
                        float m = fmaxf(bf2f(hvA[ft][reg]) + ee[reg], 0.f);
                        accA[ft][reg] = fmaf(m, mskA, accA[ft][reg]);
                    }
                }
            }
            if (doB) {
#pragma unroll
                for (int ft = 0; ft < 6; ++ft) {
                    const int fb = 16 * ft + 4 * lg;
                    f32x4 ee = *(const f32x4*)&s_bias[HH + fb];
#pragma unroll
                    for (int kt = 0; kt < 3; ++kt) {
                        bf16x8 aw = *(const bf16x8*)&s_bw2T[lr + 16 * ft][8 * lg + 32 * kt];
                        ee = __builtin_amdgcn_mfma_f32_16x16x32_bf16(aw, btB[kt], ee, 0, 0, 0);
                    }
#pragma unroll
                    for (int reg = 0; reg < 4; ++reg) {
                        float m = fmaxf(bf2f(hvB[ft][reg]) + ee[reg], 0.f);
                        accB[ft][reg] = fmaf(m, mskB, accB[ft][reg]);
                    }
                }
            }

            bA += 16; bB += 16;
        }

        // reduce + store both nodes
#pragma unroll
        for (int ft = 0; ft < 6; ++ft) {
#pragma unroll
            for (int reg = 0; reg < 4; ++reg) {
                float vA = accA[ft][reg];
                vA += __shfl_xor(vA, 1);
                vA += __shfl_xor(vA, 2);
                vA += __shfl_xor(vA, 4);
                vA += __shfl_xor(vA, 8);
                accA[ft][reg] = vA;
                float vB = accB[ft][reg];
                vB += __shfl_xor(vB, 1);
                vB += __shfl_xor(vB, 2);
                vB += __shfl_xor(vB, 4);
                vB += __shfl_xor(vB, 8);
                accB[ft][reg] = vB;
            }
        }
        if (lr == 0) {
#pragma unroll
            for (int ft = 0; ft < 6; ++ft) {
                *(f32x4*)&agg[(size_t)cA * HH + 16 * ft + 4 * lg] = accA[ft];
                *(f32x4*)&agg[(size_t)cB * HH + 16 * ft + 4 * lg] = accB[ft];
            }
        }
    }
}

// ---------------- GCN epilogue (f32 agg+self -> BN -> bf16 feats + dense hb) -----
__global__ void gcn_epilogue_kernel(
    const float* __restrict__ agg, const float* __restrict__ hbuf,
    const float* __restrict__ root, const float* __restrict__ deg,
    const float* __restrict__ gamma, const float* __restrict__ beta,
    const float* __restrict__ mean, const float* __restrict__ var,
    unsigned short* __restrict__ featsbf, unsigned short* __restrict__ hb, int N)
{
    int idx = blockIdx.x * blockDim.x + threadIdx.x;   // quad index
    if (idx >= N * (HH / 4)) return;
    int n = idx / (HH / 4), q = idx - n * (HH / 4);
    int f0 = 4 * q;
    f32x4 a  = *(const f32x4*)&agg[(size_t)n * HH + f0];
    f32x4 h  = *(const f32x4*)&hbuf[(size_t)n * HH + f0];
    f32x4 rt = *(const f32x4*)&root[f0];
    f32x4 gm = *(const f32x4*)&gamma[f0];
    f32x4 bt = *(const f32x4*)&beta[f0];
    f32x4 mn = *(const f32x4*)&mean[f0];
    f32x4 vr = *(const f32x4*)&var[f0];
    float di = 1.f / deg[n];
    float vv[4];
#pragma unroll
    for (int j = 0; j < 4; ++j) {
        float self = fmaxf(h[j] + rt[j], 0.f) * di;
        float v = fmaxf(a[j] + self, 0.f);
        vv[j] = (v - mn[j]) * rsqrtf(vr[j] + 1e-5f) * gm[j] + bt[j];
    }
    bfpack4 o;
    o.u[0] = pkbf2(vv[0], vv[1]);
    o.u[1] = pkbf2(vv[2], vv[3]);
    *(ubf16x4*)&featsbf[(size_t)n * CAT + f0] = o.v;
    *(ubf16x4*)&hb[(size_t)n * HH + f0] = o.v;
}

// ---------------- launch ----------------------------------------------------------
extern "C" void kernel_launch(void* const* d_in, const int* in_sizes, int n_in,
                              void* d_out, int out_size, void* d_ws, size_t ws_size,
                              hipStream_t stream)
{
    const float* x         = (const float*)d_in[0];
    const int*   eidx      = (const int*)d_in[1];
    const float* edge_attr = (const float*)d_in[2];
    const float* gcn_lin_w = (const float*)d_in[3];
    const float* gcn_lin_b = (const float*)d_in[4];
    const float* gcn_root  = (const float*)d_in[5];
    const float* gcn_bw1   = (const float*)d_in[6];
    const float* gcn_bb1   = (const float*)d_in[7];
    const float* gcn_bw2   = (const float*)d_in[8];
    const float* gcn_bb2   = (const float*)d_in[9];
    const float* gin_bw1   = (const float*)d_in[10];
    const float* gin_bb1   = (const float*)d_in[11];
    const float* gin_bw2   = (const float*)d_in[12];
    const float* gin_bb2   = (const float*)d_in[13];
    const float* gin_mw1   = (const float*)d_in[14];
    const float* gin_mb1   = (const float*)d_in[15];
    const float* gin_mw2   = (const float*)d_in[16];
    const float* gin_mb2   = (const float*)d_in[17];
    const float* gin_eps   = (const float*)d_in[18];
    const float* bn_gamma  = (const float*)d_in[19];
    const float* bn_beta   = (const float*)d_in[20];
    const float* bn_mean   = (const float*)d_in[21];
    const float* bn_var    = (const float*)d_in[22];
    const float* fc1_w     = (const float*)d_in[23];
    const float* fc1_b     = (const float*)d_in[24];
    const float* fc2_w     = (const float*)d_in[25];
    const float* fc2_b     = (const float*)d_in[26];
    float* out = (float*)d_out;

    const int N = in_sizes[0] / 128;   // 50000
    const int E = in_sizes[1] / 2;     // 800000
    const int* row = eidx;
    const int* col = eidx + E;

    // ws layout (bytes)
    char* ws = (char*)d_ws;
    float* deg        = (float*)(ws);                          // N f32
    float* dinv       = (float*)(ws + (size_t)256 * 1024);     // N f32
    int*   seg_start  = (int*)(ws + (size_t)512 * 1024);       // N+1
    int*   cursor     = (int*)(ws + (size_t)768 * 1024);       // N (also hist cnt)
    int*   bsum       = (int*)(ws + (size_t)1024 * 1024);      // 256
    int*   row_sorted = (int*)(ws + (size_t)1088 * 1024);      // E (3.2MB)
    unsigned short* ea_sorted = (unsigned short*)(ws + (size_t)8 * 1024 * 1024);    // E*16 bf16
    unsigned short* hb        = (unsigned short*)(ws + (size_t)34 * 1024 * 1024);   // N*96 bf16
    float* hbuf   = (float*)(ws + (size_t)44 * 1024 * 1024);   // N*96 f32
    float* agg    = (float*)(ws + (size_t)64 * 1024 * 1024);   // N*96 f32
    unsigned short* featsbf = (unsigned short*)(ws + (size_t)84 * 1024 * 1024);     // N*288 bf16
    unsigned short* r1bf    = (unsigned short*)(ws + (size_t)123 * 1024 * 1024);    // N*96 bf16

    const int ew_blocks = 1024;                     // grid-stride over node pairs
    const int q_grid = (N * (HH / 4) + 255) / 256;
    const int gemm_grid = (N + 63) / 64;
    const int e_grid = (E + 255) / 256;
    const int n_grid = (N + 255) / 256;
    const int nchunks = (N + 255) / 256;

    // ---- degrees + CSR build ----
    init_kernel<<<n_grid, 256, 0, stream>>>(deg, cursor, N);
    count_kernel<<<e_grid, 256, 0, stream>>>(row, col, deg, cursor, E);
    scan1_kernel<<<nchunks, 256, 0, stream>>>(cursor, seg_start, bsum, N);
    scan2_kernel<<<1, 256, 0, stream>>>(bsum, nchunks);
    scan3_kernel<<<(N + 256) / 256, 256, 0, stream>>>(seg_start, bsum, cursor, deg, dinv, N, E);
    scatter_ea_kernel<<<e_grid, 256, 0, stream>>>(row, col, cursor, edge_attr,
                                                  row_sorted, ea_sorted, E);

    // ---- layer 0: GCN ----
    node_gemm<128, 96, 0, 3><<<gemm_grid, 256, 0, stream>>>(
        x, 128, gcn_lin_w, gcn_lin_b, hbuf, HH, hb, N);
    edge_kernel<true><<<ew_blocks, 256, 0, stream>>>(
        ea_sorted, row_sorted, seg_start,
        gcn_bw1, gcn_bb1, gcn_bw2, gcn_bb2, hb, dinv, agg, N);
    gcn_epilogue_kernel<<<q_grid, 256, 0, stream>>>(
        agg, hbuf, gcn_root, deg, bn_gamma, bn_beta, bn_mean, bn_var, featsbf, hb, N);

    // ---- layers 1..2: GIN (edge kernel + fused MLP) ----
    for (int i = 0; i < 2; ++i) {
        edge_kernel<false><<<ew_blocks, 256, 0, stream>>>(
            ea_sorted, row_sorted, seg_start,
            gin_bw1 + (size_t)i * EDGEF * HH, gin_bb1 + i * HH,
            gin_bw2 + (size_t)i * HH * HH, gin_bb2 + i * HH,
            hb, dinv, agg, N);
        gin_mlp<<<gemm_grid, 256, 0, stream>>>(
            hb, agg, gin_eps, i,
            gin_mw1 + (size_t)i * HH * HH, gin_mb1 + i * HH,
            gin_mw2 + (size_t)i * HH * HH, gin_mb2 + i * HH,
            bn_gamma + (i + 1) * HH, bn_beta + (i + 1) * HH,
            bn_mean + (i + 1) * HH, bn_var + (i + 1) * HH,
            featsbf, i + 1, hb, N);
    }

    // ---- head ----
    node_gemm<288, 96, 1, 1><<<gemm_grid, 256, 0, stream>>>(
        featsbf, CAT, fc1_w, fc1_b, r1bf, HH, nullptr, N);
    node_gemm<96, 64, 1, 0><<<gemm_grid, 256, 0, stream>>>(
        r1bf, HH, fc2_w, fc2_b, out, 64, nullptr, N);
}

// Round 15
// 599.059 us; speedup vs baseline: 1.2892x; 1.2892x over previous
//
#include <hip/hip_runtime.h>
#include <hip/hip_bf16.h>

// NodeGCN: GCNConv + 2x GINConv (edge-attr MLPs) + BN + concat + 2-layer head.
// Round 15: REVERT to R10 best-known (596us). R11 (frag-linear LDS, -conflicts),
// R12 (DPP reduce), R13 (16-wave occupancy), R14 (2-node ILP -> spill) all
// failed to beat R10's edge kernel: it is latency-bound on the per-batch
// dependent chain (row -> h-gather -> GEMM1 -> exchange -> GEMM2) and none of
// {conflicts, reduce pipe, occupancy, ILP} bind. This is R10 verbatim.

#define HH 96
#define EDGEF 16
#define CAT (3 * HH)

typedef __attribute__((ext_vector_type(8))) short bf16x8;
typedef __attribute__((ext_vector_type(4))) float f32x4;
typedef __attribute__((ext_vector_type(4))) unsigned short ubf16x4;
typedef __attribute__((ext_vector_type(2))) unsigned uint2v;

typedef union { bf16x8 v; unsigned u[4]; } bfpack8;
typedef union { ubf16x4 v; unsigned u[2]; } bfpack4;

__device__ __forceinline__ unsigned short f2bf(float f) {
    unsigned u = __float_as_uint(f);
    u += 0x7fffu + ((u >> 16) & 1u);      // round-to-nearest-even
    return (unsigned short)(u >> 16);
}
__device__ __forceinline__ float bf2f(unsigned short s) {
    return __uint_as_float(((unsigned)s) << 16);
}
// packed f32x2 -> bf16x2 (RNE, v_cvt_pk_bf16_f32); lo 16 bits = lo input
__device__ __forceinline__ unsigned pkbf2(float lo, float hi) {
    __hip_bfloat162 b = __float22bfloat162_rn(make_float2(lo, hi));
    union { __hip_bfloat162 b2; unsigned u; } cv; cv.b2 = b; return cv.u;
}

// ---------------- unified MFMA node GEMM (layer0 / head) --------------------------
// AMODE: 0 = f32 A; 1 = bf16 A.  EPI: 0 = f32 C; 1 = relu->bf16 C; 3 = f32 C + bf16 copy
template <int K, int F, int AMODE, int EPI>
__global__ __launch_bounds__(256) void node_gemm(
    const void* __restrict__ Aptr, int lda,
    const float* __restrict__ W, const float* __restrict__ bias,
    void* __restrict__ Cptr, int ldc,
    unsigned short* __restrict__ bf_copy,
    int M)
{
    constexpr int SW = ((K * 2) % 128 == 0) ? 7 : 3;
    constexpr int NFT = F / 16;
    __shared__ __align__(16) short s_wt[F * K];

    const int tid = threadIdx.x;
    const int lane = tid & 63;
    const int w = tid >> 6;
    const int lr = lane & 15;
    const int lg = lane >> 4;

    for (int idx = tid; idx < F * K; idx += 256) {
        int f = idx / K, k = idx - f * K;
        s_wt[idx ^ ((f & SW) << 3)] = (short)f2bf(W[k * F + f]);
    }
    __syncthreads();

    const int R0 = blockIdx.x * 64 + 16 * w;
    const int Ra = min(R0 + lr, M - 1);

    f32x4 acc[NFT];
#pragma unroll
    for (int ft = 0; ft < NFT; ++ft) {
        float b = bias[16 * ft + lr];
        acc[ft][0] = b; acc[ft][1] = b; acc[ft][2] = b; acc[ft][3] = b;
    }

#pragma unroll
    for (int kt = 0; kt < K / 32; ++kt) {
        bf16x8 ae;
        if (AMODE == 0) {
            const float* ap = (const float*)Aptr + (size_t)Ra * lda + 32 * kt + 8 * lg;
            f32x4 a0 = *(const f32x4*)ap;
            f32x4 a1 = *(const f32x4*)(ap + 4);
            bfpack8 p;
            p.u[0] = pkbf2(a0[0], a0[1]); p.u[1] = pkbf2(a0[2], a0[3]);
            p.u[2] = pkbf2(a1[0], a1[1]); p.u[3] = pkbf2(a1[2], a1[3]);
            ae = p.v;
        } else {
            ae = *(const bf16x8*)((const unsigned short*)Aptr + (size_t)Ra * lda + 32 * kt + 8 * lg);
        }
#pragma unroll
        for (int ft = 0; ft < NFT; ++ft) {
            bf16x8 bw = *(const bf16x8*)&s_wt[((lr + 16 * ft) * K + 32 * kt + 8 * lg) ^ ((lr & SW) << 3)];
            acc[ft] = __builtin_amdgcn_mfma_f32_16x16x32_bf16(ae, bw, acc[ft], 0, 0, 0);
        }
    }

#pragma unroll
    for (int reg = 0; reg < 4; ++reg) {
        int r = R0 + 4 * lg + reg;
        if (r < M) {
#pragma unroll
            for (int ft = 0; ft < NFT; ++ft) {
                int col = 16 * ft + lr;
                float v = acc[ft][reg];
                if (EPI == 0) {
                    ((float*)Cptr)[(size_t)r * ldc + col] = v;
                } else if (EPI == 1) {
                    ((unsigned short*)Cptr)[(size_t)r * ldc + col] = f2bf(fmaxf(v, 0.f));
                } else {
                    ((float*)Cptr)[(size_t)r * ldc + col] = v;
                    bf_copy[(size_t)r * F + col] = f2bf(v);
                }
            }
        }
    }
}

// ---------------- fused GIN MLP: z=(1+eps)h+agg; out=BN(relu(relu(z@W1+b1)@W2+b2)) --
__global__ __launch_bounds__(256) void gin_mlp(
    const unsigned short* __restrict__ hb_in,   // dense [N][96] bf16
    const float* __restrict__ agg,              // dense [N][96] f32
    const float* __restrict__ eps_arr, int li,
    const float* __restrict__ mw1, const float* __restrict__ mb1,
    const float* __restrict__ mw2, const float* __restrict__ mb2,
    const float* __restrict__ gamma, const float* __restrict__ beta,
    const float* __restrict__ mean, const float* __restrict__ var,
    unsigned short* __restrict__ featsbf, int slot,
    unsigned short* __restrict__ hb_out,
    int M)
{
    __shared__ __align__(16) short s_w1t[96][104];   // mw1^T bf16 [f][k]
    __shared__ __align__(16) short s_w2t[96][104];   // mw2^T bf16 [f][k]
    __shared__ __align__(16) short s_z[4][16][104];  // per-wave z1 tile
    __shared__ float s_b[192];                       // mb1 | mb2

    const int tid = threadIdx.x;
    const int lane = tid & 63;
    const int w = tid >> 6;
    const int lr = lane & 15;
    const int lg = lane >> 4;

    for (int idx = tid; idx < HH * HH; idx += 256) {
        int k = idx / HH, f = idx - k * HH;
        s_w1t[f][k] = (short)f2bf(mw1[idx]);
        s_w2t[f][k] = (short)f2bf(mw2[idx]);
    }
    if (tid < HH) { s_b[tid] = mb1[tid]; s_b[HH + tid] = mb2[tid]; }
    __syncthreads();

    const int R0 = blockIdx.x * 64 + 16 * w;
    const int Ra = min(R0 + lr, M - 1);
    const float e1 = 1.f + eps_arr[li];

    // input B-frags (z^T): lane (lr,lg) holds z[row Ra(lr)][k=32kt+8lg+j]
    bf16x8 inf[3];
#pragma unroll
    for (int kt = 0; kt < 3; ++kt) {
        const unsigned short* hp = hb_in + (size_t)Ra * HH + 32 * kt + 8 * lg;
        bf16x8 h8 = *(const bf16x8*)hp;
        const float* gp = agg + (size_t)Ra * HH + 32 * kt + 8 * lg;
        f32x4 g0 = *(const f32x4*)gp;
        f32x4 g1 = *(const f32x4*)(gp + 4);
        float t0 = fmaf(e1, bf2f((unsigned short)h8[0]), g0[0]);
        float t1 = fmaf(e1, bf2f((unsigned short)h8[1]), g0[1]);
        float t2 = fmaf(e1, bf2f((unsigned short)h8[2]), g0[2]);
        float t3 = fmaf(e1, bf2f((unsigned short)h8[3]), g0[3]);
        float t4 = fmaf(e1, bf2f((unsigned short)h8[4]), g1[0]);
        float t5 = fmaf(e1, bf2f((unsigned short)h8[5]), g1[1]);
        float t6 = fmaf(e1, bf2f((unsigned short)h8[6]), g1[2]);
        float t7 = fmaf(e1, bf2f((unsigned short)h8[7]), g1[3]);
        bfpack8 p;
        p.u[0] = pkbf2(t0, t1); p.u[1] = pkbf2(t2, t3);
        p.u[2] = pkbf2(t4, t5); p.u[3] = pkbf2(t6, t7);
        inf[kt] = p.v;
    }

    // GEMM1 swapped: D = z1^T (row=feat 16ft+4lg+reg, col=node lr), mb1 C-init
#pragma unroll
    for (int ft = 0; ft < 6; ++ft) {
        f32x4 t4v = *(const f32x4*)&s_b[16 * ft + 4 * lg];
#pragma unroll
        for (int kt = 0; kt < 3; ++kt) {
            bf16x8 aw = *(const bf16x8*)&s_w1t[16 * ft + lr][32 * kt + 8 * lg];
            t4v = __builtin_amdgcn_mfma_f32_16x16x32_bf16(aw, inf[kt], t4v, 0, 0, 0);
        }
        uint2v uu;
        uu[0] = pkbf2(fmaxf(t4v[0], 0.f), fmaxf(t4v[1], 0.f));
        uu[1] = pkbf2(fmaxf(t4v[2], 0.f), fmaxf(t4v[3], 0.f));
        *(uint2v*)&s_z[w][lr][16 * ft + 4 * lg] = uu;
    }
    __builtin_amdgcn_wave_barrier();

    // GEMM2 normal: A = z1 rows (from s_z), B = mw2 (from s_w2t), mb2 C-init
    bf16x8 az[3];
#pragma unroll
    for (int kt = 0; kt < 3; ++kt)
        az[kt] = *(const bf16x8*)&s_z[w][lr][32 * kt + 8 * lg];

    f32x4 acc[6];
#pragma unroll
    for (int ft = 0; ft < 6; ++ft) {
        float b = s_b[HH + 16 * ft + lr];
        acc[ft][0] = b; acc[ft][1] = b; acc[ft][2] = b; acc[ft][3] = b;
#pragma unroll
        for (int kt = 0; kt < 3; ++kt) {
            bf16x8 bw = *(const bf16x8*)&s_w2t[16 * ft + lr][32 * kt + 8 * lg];
            acc[ft] = __builtin_amdgcn_mfma_f32_16x16x32_bf16(az[kt], bw, acc[ft], 0, 0, 0);
        }
    }

    // epilogue: BN(relu(.)) -> strided featsbf + dense hb_out
    float scale[6], shiftv[6];
#pragma unroll
    for (int ft = 0; ft < 6; ++ft) {
        int col = 16 * ft + lr;
        float s = gamma[col] * rsqrtf(var[col] + 1e-5f);
        scale[ft] = s;
        shiftv[ft] = beta[col] - mean[col] * s;
    }
#pragma unroll
    for (int reg = 0; reg < 4; ++reg) {
        int r = R0 + 4 * lg + reg;
        if (r < M) {
#pragma unroll
            for (int ft = 0; ft < 6; ++ft) {
                int col = 16 * ft + lr;
                float z = fmaxf(acc[ft][reg], 0.f) * scale[ft] + shiftv[ft];
                unsigned short zb = f2bf(z);
                featsbf[(size_t)r * CAT + slot * HH + col] = zb;
                hb_out[(size_t)r * HH + col] = zb;
            }
        }
    }
}

// ---------------- CSR build (fused) ----------------------------------------------
__global__ void init_kernel(float* __restrict__ deg, int* __restrict__ cnt, int N)
{
    int i = blockIdx.x * blockDim.x + threadIdx.x;
    if (i < N) { deg[i] = 1.f; cnt[i] = 0; }
}

__global__ void count_kernel(const int* __restrict__ row, const int* __restrict__ col,
                             float* __restrict__ deg, int* __restrict__ cnt, int E)
{
    int e = blockIdx.x * blockDim.x + threadIdx.x;
    if (e < E) {
        atomicAdd(&deg[row[e]], 1.f);
        atomicAdd(&cnt[col[e]], 1);
    }
}

__global__ void scan1_kernel(const int* __restrict__ cnt, int* __restrict__ start,
                             int* __restrict__ bsum, int N)
{
    __shared__ int s[256];
    int tid = threadIdx.x;
    int i = blockIdx.x * 256 + tid;
    int v = (i < N) ? cnt[i] : 0;
    s[tid] = v;
    __syncthreads();
#pragma unroll
    for (int off = 1; off < 256; off <<= 1) {
        int t = (tid >= off) ? s[tid - off] : 0;
        __syncthreads();
        s[tid] += t;
        __syncthreads();
    }
    if (i < N) start[i] = s[tid] - v;
    if (tid == 255) bsum[blockIdx.x] = s[255];
}

__global__ void scan2_kernel(int* __restrict__ bsum, int nb)
{
    __shared__ int s[256];
    int tid = threadIdx.x;
    int v = (tid < nb) ? bsum[tid] : 0;
    s[tid] = v;
    __syncthreads();
#pragma unroll
    for (int off = 1; off < 256; off <<= 1) {
        int t = (tid >= off) ? s[tid - off] : 0;
        __syncthreads();
        s[tid] += t;
        __syncthreads();
    }
    if (tid < nb) bsum[tid] = s[tid] - v;
}

__global__ void scan3_kernel(int* __restrict__ start, const int* __restrict__ bsum,
                             int* __restrict__ cursor,
                             const float* __restrict__ deg, float* __restrict__ dinv,
                             int N, int E)
{
    int i = blockIdx.x * blockDim.x + threadIdx.x;
    if (i < N) {
        int f = start[i] + bsum[i >> 8];
        start[i] = f;
        cursor[i] = f;
        dinv[i] = rsqrtf(deg[i]);
    } else if (i == N) {
        start[N] = E;
    }
}

// scatter + edge_attr permute+cvt fused
__global__ void scatter_ea_kernel(const int* __restrict__ row, const int* __restrict__ col,
                                  int* __restrict__ cursor,
                                  const float* __restrict__ ea,
                                  int* __restrict__ row_sorted,
                                  unsigned short* __restrict__ eas, int E)
{
    int e = blockIdx.x * blockDim.x + threadIdx.x;
    if (e >= E) return;
    int c = col[e];
    int p = atomicAdd(&cursor[c], 1);
    row_sorted[p] = row[e];
    const float* src = ea + (size_t)e * EDGEF;
    f32x4 v0 = *(const f32x4*)(src);
    f32x4 v1 = *(const f32x4*)(src + 4);
    f32x4 v2 = *(const f32x4*)(src + 8);
    f32x4 v3 = *(const f32x4*)(src + 12);
    bfpack8 o0, o1;
    o0.u[0] = pkbf2(v0[0], v0[1]); o0.u[1] = pkbf2(v0[2], v0[3]);
    o0.u[2] = pkbf2(v1[0], v1[1]); o0.u[3] = pkbf2(v1[2], v1[3]);
    o1.u[0] = pkbf2(v2[0], v2[1]); o1.u[1] = pkbf2(v2[2], v2[3]);
    o1.u[2] = pkbf2(v3[0], v3[1]); o1.u[3] = pkbf2(v3[2], v3[3]);
    *(bf16x8*)(eas + (size_t)p * EDGEF) = o0.v;
    *(bf16x8*)(eas + (size_t)p * EDGEF + 8) = o1.v;
}

// ---------------- node-centric MFMA edge kernel ----------------------------------
// One wave per destination node, (256,4). Per 16-edge batch: h gathered DIRECTLY
// into the lanes that consume it (6x8B at r*96+16ft+4lg), no LDS park, one
// wave_barrier. GEMM1 swapped (R9), b64 t-exchange, bb1/bb2 via MFMA C-init.
template <bool GCN>
__global__ __launch_bounds__(256, 4) void edge_kernel(
    const unsigned short* __restrict__ ea_sorted,
    const int* __restrict__ row_sorted,
    const int* __restrict__ seg_start,
    const float* __restrict__ bw1, const float* __restrict__ bb1,
    const float* __restrict__ bw2, const float* __restrict__ bb2,
    const unsigned short* __restrict__ hbf,
    const float* __restrict__ dinv,
    float* __restrict__ agg,
    int N)
{
    __shared__ __align__(16) short s_bw2T[96][104];   // bw2^T bf16 [f][k] 19968B
    __shared__ __align__(16) short s_bw1T[96][16];    // bw1^T bf16 [f][k]  3072B
    __shared__ __align__(16) short s_t[4][16][104];   // per-wave t tile   13312B
    __shared__ float s_bias[192];                     // bb1 | bb2            768B

    const int tid = threadIdx.x;
    const int lane = tid & 63;
    const int w = tid >> 6;
    const int lr = lane & 15;
    const int lg = lane >> 4;

    for (int idx = tid; idx < HH * HH; idx += 256) {
        int k = idx / HH, f = idx - k * HH;
        s_bw2T[f][k] = (short)f2bf(bw2[idx]);
    }
    for (int idx = tid; idx < EDGEF * HH; idx += 256) {
        int k = idx / HH, f = idx - k * HH;
        s_bw1T[f][k] = (short)f2bf(bw1[idx]);
    }
    if (tid < HH) { s_bias[tid] = bb1[tid]; s_bias[HH + tid] = bb2[tid]; }
    __syncthreads();

    // persistent bw1^T A-frags (zero for k>=16, lg>=2)
    bf16x8 bwf[6];
#pragma unroll
    for (int ft = 0; ft < 6; ++ft) {
        bf16x8 z;
#pragma unroll
        for (int j = 0; j < 8; ++j) z[j] = 0;
        if (lg < 2) z = *(const bf16x8*)&s_bw1T[lr + 16 * ft][8 * lg];
        bwf[ft] = z;
    }

    const int nwaves = gridDim.x * 4;

    for (int c = blockIdx.x * 4 + w; c < N; c += nwaves) {
        const int s0 = seg_start[c];
        const int s1 = seg_start[c + 1];
        const float dinv_c = GCN ? dinv[c] : 1.f;

        f32x4 acc[6];
#pragma unroll
        for (int ft = 0; ft < 6; ++ft) { acc[ft][0]=0.f; acc[ft][1]=0.f; acc[ft][2]=0.f; acc[ft][3]=0.f; }

        for (int b = s0; b < s1; b += 16) {
            const int epos = b + lr;
            const bool vld = (epos < s1);
            const int epc = vld ? epos : s0;
            const int r = row_sorted[epc];

            // direct h gather into epilogue lanes: lane (lr,lg) owns feats 16ft+4lg..+3
            const unsigned short* hrow = hbf + (size_t)r * HH + 4 * lg;
            ubf16x4 hv[6];
#pragma unroll
            for (int ft = 0; ft < 6; ++ft)
                hv[ft] = *(const ubf16x4*)(hrow + 16 * ft);

            const float msk = vld ? (GCN ? dinv[r] * dinv_c : 1.f) : 0.f;

            // B-frag (ea^T): k>=16 garbage x zero A = 0
            bf16x8 ae = *(const bf16x8*)(ea_sorted + (size_t)epc * EDGEF + 8 * (lg & 1));

            // GEMM1 swapped: D = t^T (row=feat 16ft+4lg+reg, col=edge lr), bb1 C-init
#pragma unroll
            for (int ft = 0; ft < 6; ++ft) {
                f32x4 ci = *(const f32x4*)&s_bias[16 * ft + 4 * lg];
                f32x4 t4 = __builtin_amdgcn_mfma_f32_16x16x32_bf16(bwf[ft], ae, ci, 0, 0, 0);
                uint2v uu;
                uu[0] = pkbf2(fmaxf(t4[0], 0.f), fmaxf(t4[1], 0.f));
                uu[1] = pkbf2(fmaxf(t4[2], 0.f), fmaxf(t4[3], 0.f));
                *(uint2v*)&s_t[w][lr][16 * ft + 4 * lg] = uu;
            }
            __builtin_amdgcn_wave_barrier();    // t writes before bt reads

            // GEMM2 B-frags: t[edge=lr][k=8lg+j+32kt]
            bf16x8 bt[3];
#pragma unroll
            for (int kt = 0; kt < 3; ++kt)
                bt[kt] = *(const bf16x8*)&s_t[w][lr][8 * lg + 32 * kt];

            // GEMM2 (swapped, bb2 C-init) + epilogue from registers
#pragma unroll
            for (int ft = 0; ft < 6; ++ft) {
                const int fb = 16 * ft + 4 * lg;
                f32x4 ee = *(const f32x4*)&s_bias[HH + fb];
#pragma unroll
                for (int kt = 0; kt < 3; ++kt) {
                    bf16x8 aw = *(const bf16x8*)&s_bw2T[lr + 16 * ft][8 * lg + 32 * kt];
                    ee = __builtin_amdgcn_mfma_f32_16x16x32_bf16(aw, bt[kt], ee, 0, 0, 0);
                }
#pragma unroll
                for (int reg = 0; reg < 4; ++reg) {
                    float m = fmaxf(bf2f(hv[ft][reg]) + ee[reg], 0.f);
                    acc[ft][reg] = fmaf(m, msk, acc[ft][reg]);
                }
            }
        }

        // reduce over the 16-edge lane dimension
#pragma unroll
        for (int ft = 0; ft < 6; ++ft) {
#pragma unroll
            for (int reg = 0; reg < 4; ++reg) {
                float v = acc[ft][reg];
                v += __shfl_xor(v, 1);
                v += __shfl_xor(v, 2);
                v += __shfl_xor(v, 4);
                v += __shfl_xor(v, 8);
                acc[ft][reg] = v;
            }
        }
        if (lr == 0) {
#pragma unroll
            for (int ft = 0; ft < 6; ++ft)
                *(f32x4*)&agg[(size_t)c * HH + 16 * ft + 4 * lg] = acc[ft];
        }
    }
}

// ---------------- GCN epilogue (f32 agg+self -> BN -> bf16 feats + dense hb) -----
__global__ void gcn_epilogue_kernel(
    const float* __restrict__ agg, const float* __restrict__ hbuf,
    const float* __restrict__ root, const float* __restrict__ deg,
    const float* __restrict__ gamma, const float* __restrict__ beta,
    const float* __restrict__ mean, const float* __restrict__ var,
    unsigned short* __restrict__ featsbf, unsigned short* __restrict__ hb, int N)
{
    int idx = blockIdx.x * blockDim.x + threadIdx.x;   // quad index
    if (idx >= N * (HH / 4)) return;
    int n = idx / (HH / 4), q = idx - n * (HH / 4);
    int f0 = 4 * q;
    f32x4 a  = *(const f32x4*)&agg[(size_t)n * HH + f0];
    f32x4 h  = *(const f32x4*)&hbuf[(size_t)n * HH + f0];
    f32x4 rt = *(const f32x4*)&root[f0];
    f32x4 gm = *(const f32x4*)&gamma[f0];
    f32x4 bt = *(const f32x4*)&beta[f0];
    f32x4 mn = *(const f32x4*)&mean[f0];
    f32x4 vr = *(const f32x4*)&var[f0];
    float di = 1.f / deg[n];
    float vv[4];
#pragma unroll
    for (int j = 0; j < 4; ++j) {
        float self = fmaxf(h[j] + rt[j], 0.f) * di;
        float v = fmaxf(a[j] + self, 0.f);
        vv[j] = (v - mn[j]) * rsqrtf(vr[j] + 1e-5f) * gm[j] + bt[j];
    }
    bfpack4 o;
    o.u[0] = pkbf2(vv[0], vv[1]);
    o.u[1] = pkbf2(vv[2], vv[3]);
    *(ubf16x4*)&featsbf[(size_t)n * CAT + f0] = o.v;
    *(ubf16x4*)&hb[(size_t)n * HH + f0] = o.v;
}

// ---------------- launch ----------------------------------------------------------
extern "C" void kernel_launch(void* const* d_in, const int* in_sizes, int n_in,
                              void* d_out, int out_size, void* d_ws, size_t ws_size,
                              hipStream_t stream)
{
    const float* x         = (const float*)d_in[0];
    const int*   eidx      = (const int*)d_in[1];
    const float* edge_attr = (const float*)d_in[2];
    const float* gcn_lin_w = (const float*)d_in[3];
    const float* gcn_lin_b = (const float*)d_in[4];
    const float* gcn_root  = (const float*)d_in[5];
    const float* gcn_bw1   = (const float*)d_in[6];
    const float* gcn_bb1   = (const float*)d_in[7];
    const float* gcn_bw2   = (const float*)d_in[8];
    const float* gcn_bb2   = (const float*)d_in[9];
    const float* gin_bw1   = (const float*)d_in[10];
    const float* gin_bb1   = (const float*)d_in[11];
    const float* gin_bw2   = (const float*)d_in[12];
    const float* gin_bb2   = (const float*)d_in[13];
    const float* gin_mw1   = (const float*)d_in[14];
    const float* gin_mb1   = (const float*)d_in[15];
    const float* gin_mw2   = (const float*)d_in[16];
    const float* gin_mb2   = (const float*)d_in[17];
    const float* gin_eps   = (const float*)d_in[18];
    const float* bn_gamma  = (const float*)d_in[19];
    const float* bn_beta   = (const float*)d_in[20];
    const float* bn_mean   = (const float*)d_in[21];
    const float* bn_var    = (const float*)d_in[22];
    const float* fc1_w     = (const float*)d_in[23];
    const float* fc1_b     = (const float*)d_in[24];
    const float* fc2_w     = (const float*)d_in[25];
    const float* fc2_b     = (const float*)d_in[26];
    float* out = (float*)d_out;

    const int N = in_sizes[0] / 128;   // 50000
    const int E = in_sizes[1] / 2;     // 800000
    const int* row = eidx;
    const int* col = eidx + E;

    // ws layout (bytes)
    char* ws = (char*)d_ws;
    float* deg        = (float*)(ws);                          // N f32
    float* dinv       = (float*)(ws + (size_t)256 * 1024);     // N f32
    int*   seg_start  = (int*)(ws + (size_t)512 * 1024);       // N+1
    int*   cursor     = (int*)(ws + (size_t)768 * 1024);       // N (also hist cnt)
    int*   bsum       = (int*)(ws + (size_t)1024 * 1024);      // 256
    int*   row_sorted = (int*)(ws + (size_t)1088 * 1024);      // E (3.2MB)
    unsigned short* ea_sorted = (unsigned short*)(ws + (size_t)8 * 1024 * 1024);    // E*16 bf16
    unsigned short* hb        = (unsigned short*)(ws + (size_t)34 * 1024 * 1024);   // N*96 bf16
    float* hbuf   = (float*)(ws + (size_t)44 * 1024 * 1024);   // N*96 f32
    float* agg    = (float*)(ws + (size_t)64 * 1024 * 1024);   // N*96 f32
    unsigned short* featsbf = (unsigned short*)(ws + (size_t)84 * 1024 * 1024);     // N*288 bf16
    unsigned short* r1bf    = (unsigned short*)(ws + (size_t)123 * 1024 * 1024);    // N*96 bf16

    const int ew_blocks = 1024;                     // 4 blocks/CU x 256 CU
    const int q_grid = (N * (HH / 4) + 255) / 256;
    const int gemm_grid = (N + 63) / 64;
    const int e_grid = (E + 255) / 256;
    const int n_grid = (N + 255) / 256;
    const int nchunks = (N + 255) / 256;

    // ---- degrees + CSR build ----
    init_kernel<<<n_grid, 256, 0, stream>>>(deg, cursor, N);
    count_kernel<<<e_grid, 256, 0, stream>>>(row, col, deg, cursor, E);
    scan1_kernel<<<nchunks, 256, 0, stream>>>(cursor, seg_start, bsum, N);
    scan2_kernel<<<1, 256, 0, stream>>>(bsum, nchunks);
    scan3_kernel<<<(N + 256) / 256, 256, 0, stream>>>(seg_start, bsum, cursor, deg, dinv, N, E);
    scatter_ea_kernel<<<e_grid, 256, 0, stream>>>(row, col, cursor, edge_attr,
                                                  row_sorted, ea_sorted, E);

    // ---- layer 0: GCN ----
    node_gemm<128, 96, 0, 3><<<gemm_grid, 256, 0, stream>>>(
        x, 128, gcn_lin_w, gcn_lin_b, hbuf, HH, hb, N);
    edge_kernel<true><<<ew_blocks, 256, 0, stream>>>(
        ea_sorted, row_sorted, seg_start,
        gcn_bw1, gcn_bb1, gcn_bw2, gcn_bb2, hb, dinv, agg, N);
    gcn_epilogue_kernel<<<q_grid, 256, 0, stream>>>(
        agg, hbuf, gcn_root, deg, bn_gamma, bn_beta, bn_mean, bn_var, featsbf, hb, N);

    // ---- layers 1..2: GIN (edge kernel + fused MLP) ----
    for (int i = 0; i < 2; ++i) {
        edge_kernel<false><<<ew_blocks, 256, 0, stream>>>(
            ea_sorted, row_sorted, seg_start,
            gin_bw1 + (size_t)i * EDGEF * HH, gin_bb1 + i * HH,
            gin_bw2 + (size_t)i * HH * HH, gin_bb2 + i * HH,
            hb, dinv, agg, N);
        gin_mlp<<<gemm_grid, 256, 0, stream>>>(
            hb, agg, gin_eps, i,
            gin_mw1 + (size_t)i * HH * HH, gin_mb1 + i * HH,
            gin_mw2 + (size_t)i * HH * HH, gin_mb2 + i * HH,
            bn_gamma + (i + 1) * HH, bn_beta + (i + 1) * HH,
            bn_mean + (i + 1) * HH, bn_var + (i + 1) * HH,
            featsbf, i + 1, hb, N);
    }

    // ---- head ----
    node_gemm<288, 96, 1, 1><<<gemm_grid, 256, 0, stream>>>(
        featsbf, CAT, fc1_w, fc1_b, r1bf, HH, nullptr, N);
    node_gemm<96, 64, 1, 0><<<gemm_grid, 256, 0, stream>>>(
        r1bf, HH, fc2_w, fc2_b, out, 64, nullptr, N);
}